// Round 3
// baseline (1219.741 us; speedup 1.0000x reference)
//
#include <hip/hip_runtime.h>

// f32 end-to-end (R2-verified: f32 I/O, threshold needs f32 math; no fp32 MFMA on
// CDNA4 -> vector ALU, 157 TF ceiling). R3: register-blocked broadcast tiling.
// Score loop: per-thread 2t x 8s, q via 8-way-broadcast b64, k via b128 -> VALU-bound.
// PV: P stays in registers, broadcast via __shfl (no sP LDS, no extra barrier).

typedef float f32x4 __attribute__((ext_vector_type(4)));
typedef float f32x2 __attribute__((ext_vector_type(2)));

#define B_   16
#define D_   192
#define T_   4096
#define BANK 1000
#define SP   1024
#define DK   96
#define SCALE 0.10206207261596577f   // 1/sqrt(96)

// ---------------- K/V projection (tiny) ----------------
// kws: [h][96 i][1024 s]   vws: [h][1024 s][96 i]
__global__ __launch_bounds__(256) void kv_kernel(
    const float* __restrict__ mb, const float* __restrict__ Wk, const float* __restrict__ bk,
    const float* __restrict__ Wv, const float* __restrict__ bv,
    float* __restrict__ kws, float* __restrict__ vws) {
  int s = blockIdx.x * 256 + threadIdx.x;
  int o = blockIdx.y;
  int h = o / DK, i = o % DK;
  float ak = 0.f, av = 0.f;
  if (s < BANK) {
    ak = bk[o]; av = bv[o];
    for (int c = 0; c < D_; ++c) {
      float m = mb[c * BANK + s];
      ak += Wk[o * D_ + c] * m;
      av += Wv[o * D_ + c] * m;
    }
  }
  kws[(h * DK + i) * SP + s] = ak;
  vws[(h * SP + s) * DK + i] = av;
}

// ---------------- projection: Y[b][o][t] = W X + bias ----------------
// Block [64 o][64 t]; wave = 16 o x 64 t; per-thread 2o x 8t.
// sWt [192 c][64 o] staged once (48 KB); sX [64 c][64 t] per chunk (16 KB). 64 KB total.
__global__ __launch_bounds__(256) void proj_kernel(
    const float* __restrict__ X, const float* __restrict__ W,
    const float* __restrict__ bias, float* __restrict__ Y) {
  __shared__ __align__(16) float sWt[192 * 64];
  __shared__ __align__(16) float sX[64 * 64];
  const int tid = threadIdx.x;
  const int t0 = blockIdx.x * 64, o0 = blockIdx.y * 64, b = blockIdx.z;
  const int lane = tid & 63, wv = tid >> 6;
  const int o_l = lane >> 3, t_l = lane & 7;
  const int wo = wv * 16;                    // wave's o-base within 64-o tile

  // stage W^T once: 64 rows(o) x 192 c -> sWt[c][o]
#pragma unroll
  for (int r = 0; r < 12; ++r) {
    int g = tid + 256 * r;                   // 3072 f32x4 groups
    int row = g / 48, c4 = g % 48;
    f32x4 w = *(const f32x4*)&W[(o0 + row) * D_ + 4 * c4];
#pragma unroll
    for (int u = 0; u < 4; ++u) sWt[(4 * c4 + u) * 64 + row] = w[u];
  }

  float acc[2][8] = {};
  for (int c0 = 0; c0 < D_; c0 += 64) {
    __syncthreads();
#pragma unroll
    for (int r = 0; r < 4; ++r) {            // stage X chunk [64 c][64 t]
      int g = tid + 256 * r;
      int cp = g >> 4, t4 = g & 15;
      *(f32x4*)&sX[cp * 64 + 4 * t4] =
          *(const f32x4*)&X[((size_t)b * D_ + c0 + cp) * T_ + t0 + 4 * t4];
    }
    __syncthreads();
    for (int c = 0; c < 64; ++c) {
      f32x2 w2 = *(const f32x2*)&sWt[(c0 + c) * 64 + wo + o_l * 2];  // 8-way bcast
      f32x4 xa = *(const f32x4*)&sX[c * 64 + t_l * 8];
      f32x4 xb = *(const f32x4*)&sX[c * 64 + t_l * 8 + 4];
#pragma unroll
      for (int j = 0; j < 2; ++j) {
#pragma unroll
        for (int a = 0; a < 4; ++a) {
          acc[j][a]     += w2[j] * xa[a];
          acc[j][4 + a] += w2[j] * xb[a];
        }
      }
    }
  }
#pragma unroll
  for (int j = 0; j < 2; ++j) {
    float bb = bias[o0 + wo + o_l * 2 + j];
    f32x4 ya, yb;
#pragma unroll
    for (int a = 0; a < 4; ++a) { ya[a] = acc[j][a] + bb; yb[a] = acc[j][4 + a] + bb; }
    float* yp = &Y[((size_t)b * D_ + o0 + wo + o_l * 2 + j) * T_ + t0 + t_l * 8];
    *(f32x4*)yp = ya;
    *(f32x4*)(yp + 4) = yb;
  }
}

// ---------------- flash attention, f32, online softmax ----------------
// Block = (b, h, 64 t); 4 waves, wave = 16t x full 64-s chunk.
// Lane grid: t_l = lane>>3 (2 t each), s_l = lane&7 (8 s each / 12 i each in PV).
// m/l/alpha wave-private in registers (rows live within 8-lane groups).
__global__ __launch_bounds__(256) void attn_kernel(
    const float* __restrict__ qws, const float* __restrict__ kws,
    const float* __restrict__ vws, float* __restrict__ ows) {
  __shared__ __align__(16) float sQ[96 * 64];   // [i][t]  24 KB
  __shared__ __align__(16) float sK[96 * 64];   // [i][s'] 24 KB
  __shared__ __align__(16) float sV[64 * 96];   // [s'][i] 24 KB

  const int tid = threadIdx.x;
  const int t0 = blockIdx.x * 64, h = blockIdx.y, b = blockIdx.z;
  const int lane = tid & 63, wv = tid >> 6;
  const int t_l = lane >> 3, s_l = lane & 7;
  const int tw = wv * 16;

  const float* qbase = qws + ((size_t)(b * D_ + h * DK)) * T_ + t0;
  const float* kb = kws + (size_t)h * DK * SP;
  const float* vb = vws + (size_t)h * SP * DK;

#pragma unroll
  for (int r = 0; r < 6; ++r) {               // stage Q [96][64]
    int idx = tid + 256 * r;
    int row = idx >> 4, c4 = idx & 15;
    *(f32x4*)&sQ[row * 64 + 4 * c4] = *(const f32x4*)&qbase[(size_t)row * T_ + 4 * c4];
  }

  float o_acc[2][12] = {};
  float p[2][8];
  float m_run[2] = {-1e30f, -1e30f}, l_run[2] = {0.f, 0.f};
  const int src_base = lane & 56;             // t_l*8

  for (int ch = 0; ch < 16; ++ch) {
    const int s0 = ch * 64;
    __syncthreads();                          // prev chunk's readers done
#pragma unroll
    for (int r = 0; r < 6; ++r) {             // stage K chunk [96][64]
      int idx = tid + 256 * r;
      int row = idx >> 4, c4 = idx & 15;
      *(f32x4*)&sK[row * 64 + 4 * c4] = *(const f32x4*)&kb[(size_t)row * SP + s0 + 4 * c4];
    }
#pragma unroll
    for (int r = 0; r < 6; ++r) {             // stage V chunk [64][96] (flat copy)
      int idx = tid + 256 * r;
      *(f32x4*)&sV[idx * 4] = *(const f32x4*)&vb[(size_t)s0 * DK + idx * 4];
    }
    __syncthreads();

    // ---- scores: 2t x 8s per thread ----
    float S[2][8] = {};
    for (int i = 0; i < DK; ++i) {
      f32x2 q2 = *(const f32x2*)&sQ[i * 64 + tw + t_l * 2];      // 8-way bcast
      f32x4 ka = *(const f32x4*)&sK[i * 64 + s_l * 8];
      f32x4 kc = *(const f32x4*)&sK[i * 64 + s_l * 8 + 4];
#pragma unroll
      for (int j = 0; j < 2; ++j) {
#pragma unroll
        for (int m = 0; m < 4; ++m) {
          S[j][m]     += q2[j] * ka[m];
          S[j][4 + m] += q2[j] * kc[m];
        }
      }
    }
    if (ch == 15) {                           // mask s >= BANK (only last chunk)
#pragma unroll
      for (int m = 0; m < 8; ++m)
        if (s0 + s_l * 8 + m >= BANK) { S[0][m] = -1e30f; S[1][m] = -1e30f; }
    }

    // ---- online softmax (wave-private: row = 8 s_l lanes) ----
#pragma unroll
    for (int j = 0; j < 2; ++j) {
      float mc = S[j][0];
#pragma unroll
      for (int m = 1; m < 8; ++m) mc = fmaxf(mc, S[j][m]);
      mc = fmaxf(mc, __shfl_xor(mc, 1, 64));
      mc = fmaxf(mc, __shfl_xor(mc, 2, 64));
      mc = fmaxf(mc, __shfl_xor(mc, 4, 64));
      float mn = fmaxf(m_run[j], mc);
      float al = __expf((m_run[j] - mn) * SCALE);
      m_run[j] = mn;
      float ls = 0.f;
#pragma unroll
      for (int m = 0; m < 8; ++m) { p[j][m] = __expf((S[j][m] - mn) * SCALE); ls += p[j][m]; }
      ls += __shfl_xor(ls, 1, 64);
      ls += __shfl_xor(ls, 2, 64);
      ls += __shfl_xor(ls, 4, 64);
      l_run[j] = l_run[j] * al + ls;
#pragma unroll
      for (int k = 0; k < 12; ++k) o_acc[j][k] *= al;
    }

    // ---- PV: out[2t][12i] += p[t][s] * v[s][i]; p broadcast via shfl ----
    for (int sg = 0; sg < 8; ++sg) {
      const int src = src_base | sg;
#pragma unroll
      for (int mm = 0; mm < 8; ++mm) {
        int s = sg * 8 + mm;
        float p0 = __shfl(p[0][mm], src, 64);
        float p1 = __shfl(p[1][mm], src, 64);
        const float* vr = &sV[s * 96 + s_l * 12];
        f32x4 v0 = *(const f32x4*)(vr);
        f32x4 v1 = *(const f32x4*)(vr + 4);
        f32x4 v2 = *(const f32x4*)(vr + 8);
#pragma unroll
        for (int a = 0; a < 4; ++a) {
          o_acc[0][a]     += p0 * v0[a];  o_acc[1][a]     += p1 * v0[a];
          o_acc[0][4 + a] += p0 * v1[a];  o_acc[1][4 + a] += p1 * v1[a];
          o_acc[0][8 + a] += p0 * v2[a];  o_acc[1][8 + a] += p1 * v2[a];
        }
      }
    }
  }

  // ---- epilogue ----
  float inv0 = 1.0f / l_run[0], inv1 = 1.0f / l_run[1];
  size_t obase = ((size_t)(b * D_ + h * DK)) * T_ + t0 + tw + t_l * 2;
#pragma unroll
  for (int k = 0; k < 12; ++k) {
    int i = s_l * 12 + k;
    f32x2 y; y[0] = o_acc[0][k] * inv0; y[1] = o_acc[1][k] * inv1;
    *(f32x2*)&ows[obase + (size_t)i * T_] = y;
  }
}

extern "C" void kernel_launch(void* const* d_in, const int* in_sizes, int n_in,
                              void* d_out, int out_size, void* d_ws, size_t ws_size,
                              hipStream_t stream) {
  const float* z  = (const float*)d_in[0];
  const float* mb = (const float*)d_in[1];
  const float* Wq = (const float*)d_in[2];
  const float* bq = (const float*)d_in[3];
  const float* Wk = (const float*)d_in[4];
  const float* bk = (const float*)d_in[5];
  const float* Wv = (const float*)d_in[6];
  const float* bv = (const float*)d_in[7];
  const float* Wo = (const float*)d_in[8];
  const float* bo = (const float*)d_in[9];
  float* out = (float*)d_out;

  float* kws = (float*)d_ws;
  float* vws = kws + 2 * DK * SP;
  float* qws = vws + 2 * SP * DK;
  float* ows = qws + (size_t)B_ * D_ * T_;

  kv_kernel  <<<dim3(SP / 256, D_),   256, 0, stream>>>(mb, Wk, bk, Wv, bv, kws, vws);
  proj_kernel<<<dim3(T_ / 64, 3, B_), 256, 0, stream>>>(z, Wq, bq, qws);
  attn_kernel<<<dim3(T_ / 64, 2, B_), 256, 0, stream>>>(qws, kws, vws, ows);
  proj_kernel<<<dim3(T_ / 64, 3, B_), 256, 0, stream>>>(ows, Wo, bo, out);
}

// Round 4
// 395.201 us; speedup vs baseline: 3.0864x; 3.0864x over previous
//
#include <hip/hip_runtime.h>

// R4: bf16-MFMA flash attention (error budget: pass @1.95e-3 vs thr 1.93e-2 in f32;
// bf16 Q/K/V/P adds ~1e-3 -> fits). Softmax + accumulation stay f32.
// Projections: R2 kernel (known 70us). f32 I/O throughout (R2-verified).

typedef float  f32x4  __attribute__((ext_vector_type(4)));
typedef float  f32x2  __attribute__((ext_vector_type(2)));
typedef __bf16 bf16;
typedef __bf16 bf16x2 __attribute__((ext_vector_type(2)));
typedef __bf16 bf16x8 __attribute__((ext_vector_type(8)));

#define B_   16
#define D_   192
#define T_   4096
#define BANK 1000
#define SP   1024
#define DK   96
#define SCALE 0.10206207261596577f   // 1/sqrt(96)

// LDS strides (elements)
#define QTS 104   // qt [64 t][96 i] bf16, stride 104 (52 banks -> 2-way, free)
#define KTS 104   // kt [64 s][96 i] bf16
#define VTS 72    // vt [96 i][64 s] bf16 (36 banks -> 2-way)
#define SSS 68    // sS [64 t][64 s] f32 ; sO overlay [96 i][64 t] f32
#define SPS 72    // sP [64 t][64 s] bf16

// ---------------- K/V projection -> bf16, MFMA-native layouts ----------------
// ktg: [h][1024 s][96 i]  (QK B-operand: B[k=i][n=s]=K[s][i], read 8 i contig)
// vtg: [h][96 i][1024 s]  (PV B-operand: B[k=s][n=i]=V[s][i], read 8 s contig)
__global__ __launch_bounds__(256) void kv_kernel(
    const float* __restrict__ mb, const float* __restrict__ Wk, const float* __restrict__ bk,
    const float* __restrict__ Wv, const float* __restrict__ bv,
    bf16* __restrict__ ktg, bf16* __restrict__ vtg) {
  int s = blockIdx.x * 256 + threadIdx.x;
  int o = blockIdx.y;
  int h = o / DK, i = o % DK;
  float ak = 0.f, av = 0.f;
  if (s < BANK) {
    ak = bk[o]; av = bv[o];
    for (int c = 0; c < D_; ++c) {
      float m = mb[c * BANK + s];
      ak += Wk[o * D_ + c] * m;
      av += Wv[o * D_ + c] * m;
    }
  }
  ktg[(size_t)(h * SP + s) * DK + i] = (bf16)ak;   // zero pad rows s>=1000
  vtg[(size_t)(h * DK + i) * SP + s] = (bf16)av;
}

// ---------------- projection (R2 kernel, f32): Y[b][o][t] = W X + bias ----------------
#define PSW 68
__global__ __launch_bounds__(256) void proj_kernel(
    const float* __restrict__ X, const float* __restrict__ W,
    const float* __restrict__ bias, float* __restrict__ Y) {
  __shared__ __align__(16) float sW[32 * PSW];
  __shared__ __align__(16) float sX[32 * PSW];
  const int tid = threadIdx.x;
  const int t0 = blockIdx.x * 64, o0 = blockIdx.y * 64, b = blockIdx.z;
  const int o_thr = tid >> 4, t_thr = tid & 15;
  float acc[4][4] = {};
  for (int c0 = 0; c0 < D_; c0 += 32) {
    __syncthreads();
#pragma unroll
    for (int r = 0; r < 2; ++r) {
      int idx = tid + 256 * r;
      int op = idx >> 3, c4 = idx & 7;
      f32x4 w = *(const f32x4*)&W[(o0 + op) * D_ + c0 + 4 * c4];
#pragma unroll
      for (int u = 0; u < 4; ++u) sW[(4 * c4 + u) * PSW + op] = w[u];
    }
#pragma unroll
    for (int r = 0; r < 2; ++r) {
      int idx = tid + 256 * r;
      int cp = idx >> 4, t4 = idx & 15;
      *(f32x4*)&sX[cp * PSW + 4 * t4] =
          *(const f32x4*)&X[((size_t)b * D_ + c0 + cp) * T_ + t0 + 4 * t4];
    }
    __syncthreads();
    for (int cp = 0; cp < 32; ++cp) {
      f32x4 w4 = *(const f32x4*)&sW[cp * PSW + 4 * o_thr];
      f32x4 x4 = *(const f32x4*)&sX[cp * PSW + 4 * t_thr];
#pragma unroll
      for (int j = 0; j < 4; ++j)
#pragma unroll
        for (int a = 0; a < 4; ++a) acc[j][a] += w4[j] * x4[a];
    }
  }
#pragma unroll
  for (int j = 0; j < 4; ++j) {
    float bb = bias[o0 + 4 * o_thr + j];
    f32x4 y;
#pragma unroll
    for (int a = 0; a < 4; ++a) y[a] = acc[j][a] + bb;
    *(f32x4*)&Y[((size_t)b * D_ + o0 + 4 * o_thr + j) * T_ + t0 + 4 * t_thr] = y;
  }
}

// ---------------- bf16-MFMA flash attention ----------------
// Block = (b, h, 64 t), 4 waves, wave owns 16 t. Chunk = 64 s.
// mfma_f32_16x16x32_bf16 layouts (m89-verified):
//   A: lane holds A[m=lane&15][k=quad*8+j]; B: lane holds B[k=quad*8+j][n=lane&15]
//   D: row = quad*4+reg, col = lane&15
__global__ __launch_bounds__(256) void attn_kernel(
    const float* __restrict__ qws, const bf16* __restrict__ ktg,
    const bf16* __restrict__ vtg, float* __restrict__ ows) {
  __shared__ __align__(16) char smem[67840];
  bf16*  qt = (bf16*)smem;                 // 64*104*2 = 13312
  bf16*  kt = (bf16*)(smem + 13312);       // 64*104*2 = 13312
  bf16*  vt = (bf16*)(smem + 26624);       // 96*72*2  = 13824
  float* sS = (float*)(smem + 40448);      // 64*68*4  = 17408
  bf16*  sP = (bf16*)(smem + 57856);       // 64*72*2  = 9216
  float* sM = (float*)(smem + 67072);      // 64*4
  float* sL  = sM + 64;
  float* sAl = sL + 64;                    // ends at 67840
  float* sO = (float*)smem;                // overlay qt|kt: 96*68*4 = 26112 <= 26624

  const int tid = threadIdx.x;
  const int t0 = blockIdx.x * 64, h = blockIdx.y, b = blockIdx.z;
  const int lane = tid & 63, wv = tid >> 6;
  const int l15 = lane & 15, quad = lane >> 4;
  const int tw = wv * 16;

  // stage Q once: f32 [b][h*96+i][t0+t] -> bf16 qt[t][i] (coalesced reads along t)
  for (int r = 0; r < 24; ++r) {
    int idx = tid + 256 * r;               // 6144 = 96 i x 64 t
    int i = idx >> 6, t = idx & 63;
    float v = qws[((size_t)(b * D_ + h * DK + i)) * T_ + t0 + t];
    qt[t * QTS + i] = (bf16)v;
  }
  if (tid < 64) { sM[tid] = -1e30f; sL[tid] = 0.f; }

  f32x4 oacc[6];
#pragma unroll
  for (int n = 0; n < 6; ++n) oacc[n] = (f32x4){0.f, 0.f, 0.f, 0.f};

  const bf16* kb = ktg + (size_t)h * SP * DK;
  const bf16* vb = vtg + (size_t)h * DK * SP;

  for (int ch = 0; ch < 16; ++ch) {
    const int s0 = ch * 64;
    __syncthreads();                       // (A) prev chunk readers done
#pragma unroll
    for (int r = 0; r < 3; ++r) {          // stage K chunk: kt[s][i]
      int g = tid + 256 * r;               // 768 groups of 8
      int s = g / 12, off = (g % 12) * 8;
      *(bf16x8*)&kt[s * KTS + off] = *(const bf16x8*)&kb[(size_t)(s0 + s) * DK + off];
    }
#pragma unroll
    for (int r = 0; r < 3; ++r) {          // stage V chunk: vt[i][s']
      int g = tid + 256 * r;
      int i = g >> 3, off = (g & 7) * 8;
      *(bf16x8*)&vt[i * VTS + off] = *(const bf16x8*)&vb[(size_t)i * SP + s0 + off];
    }
    __syncthreads();                       // (B)

    // ---- QK^T: wave t-tile [tw,tw+16) x s [0,64) ----
    f32x4 sacc[4];
#pragma unroll
    for (int n = 0; n < 4; ++n) sacc[n] = (f32x4){0.f, 0.f, 0.f, 0.f};
#pragma unroll
    for (int k = 0; k < 3; ++k) {
      bf16x8 af = *(const bf16x8*)&qt[(tw + l15) * QTS + k * 32 + quad * 8];
#pragma unroll
      for (int n = 0; n < 4; ++n) {
        bf16x8 bfm = *(const bf16x8*)&kt[(n * 16 + l15) * KTS + k * 32 + quad * 8];
        sacc[n] = __builtin_amdgcn_mfma_f32_16x16x32_bf16(af, bfm, sacc[n], 0, 0, 0);
      }
    }
#pragma unroll
    for (int n = 0; n < 4; ++n)
#pragma unroll
      for (int r = 0; r < 4; ++r)
        sS[(tw + quad * 4 + r) * SSS + n * 16 + l15] = sacc[n][r];
    __syncthreads();                       // (C)

    // ---- online softmax: 4 lanes per row, 16 s each ----
    {
      int row = tid >> 2, sl = tid & 3;    // partners within same wave
      float sv[16];
#pragma unroll
      for (int c = 0; c < 4; ++c)
        *(f32x4*)&sv[4 * c] = *(const f32x4*)&sS[row * SSS + sl * 16 + 4 * c];
      if (ch == 15) {                      // mask s >= BANK (in-chunk idx >= 40)
#pragma unroll
        for (int j = 0; j < 16; ++j)
          if (sl * 16 + j >= 40) sv[j] = -1e30f;
      }
      float mc = sv[0];
#pragma unroll
      for (int j = 1; j < 16; ++j) mc = fmaxf(mc, sv[j]);
      mc = fmaxf(mc, __shfl_xor(mc, 1, 64));
      mc = fmaxf(mc, __shfl_xor(mc, 2, 64));
      float mold = sM[row];
      float mn = fmaxf(mold, mc);
      float p[16], ls = 0.f;
#pragma unroll
      for (int j = 0; j < 16; ++j) { p[j] = __expf((sv[j] - mn) * SCALE); ls += p[j]; }
      ls += __shfl_xor(ls, 1, 64);
      ls += __shfl_xor(ls, 2, 64);
#pragma unroll
      for (int j = 0; j < 8; ++j) {
        bf16x2 pp; pp[0] = (bf16)p[2 * j]; pp[1] = (bf16)p[2 * j + 1];
        *(bf16x2*)&sP[row * SPS + sl * 16 + 2 * j] = pp;
      }
      if (sl == 0) {
        float al = __expf((mold - mn) * SCALE);
        sAl[row] = al; sM[row] = mn; sL[row] = sL[row] * al + ls;
      }
    }
    __syncthreads();                       // (D)

    // ---- rescale + PV MFMA ----
    float al[4];
#pragma unroll
    for (int r = 0; r < 4; ++r) al[r] = sAl[tw + quad * 4 + r];
#pragma unroll
    for (int n = 0; n < 6; ++n)
#pragma unroll
      for (int r = 0; r < 4; ++r) oacc[n][r] *= al[r];
#pragma unroll
    for (int k = 0; k < 2; ++k) {
      bf16x8 pa = *(const bf16x8*)&sP[(tw + l15) * SPS + k * 32 + quad * 8];
#pragma unroll
      for (int n = 0; n < 6; ++n) {
        bf16x8 vf = *(const bf16x8*)&vt[(n * 16 + l15) * VTS + k * 32 + quad * 8];
        oacc[n] = __builtin_amdgcn_mfma_f32_16x16x32_bf16(pa, vf, oacc[n], 0, 0, 0);
      }
    }
  }

  // ---- epilogue: /l, transpose via sO, coalesced f32 store ----
  float linv[4];
#pragma unroll
  for (int r = 0; r < 4; ++r) linv[r] = 1.0f / sL[tw + quad * 4 + r];
  __syncthreads();                         // all waves past last reads of qt/kt region
#pragma unroll
  for (int n = 0; n < 6; ++n)
#pragma unroll
    for (int r = 0; r < 4; ++r)
      sO[(n * 16 + l15) * SSS + tw + quad * 4 + r] = oacc[n][r] * linv[r];
  __syncthreads();
  for (int r = 0; r < 24; ++r) {
    int idx = tid + 256 * r;
    int i = idx >> 6, t = idx & 63;
    ows[((size_t)(b * D_ + h * DK + i)) * T_ + t0 + t] = sO[i * SSS + t];
  }
}

extern "C" void kernel_launch(void* const* d_in, const int* in_sizes, int n_in,
                              void* d_out, int out_size, void* d_ws, size_t ws_size,
                              hipStream_t stream) {
  const float* z  = (const float*)d_in[0];
  const float* mb = (const float*)d_in[1];
  const float* Wq = (const float*)d_in[2];
  const float* bq = (const float*)d_in[3];
  const float* Wk = (const float*)d_in[4];
  const float* bk = (const float*)d_in[5];
  const float* Wv = (const float*)d_in[6];
  const float* bv = (const float*)d_in[7];
  const float* Wo = (const float*)d_in[8];
  const float* bo = (const float*)d_in[9];
  float* out = (float*)d_out;

  // ws: ktg bf16 2*1024*96 | vtg bf16 2*96*1024 | qws f32 16*192*4096 | ows f32 same
  bf16* ktg = (bf16*)d_ws;
  bf16* vtg = ktg + 2 * SP * DK;
  float* qws = (float*)(vtg + 2 * DK * SP);
  float* ows = qws + (size_t)B_ * D_ * T_;

  kv_kernel  <<<dim3(SP / 256, D_),   256, 0, stream>>>(mb, Wk, bk, Wv, bv, ktg, vtg);
  proj_kernel<<<dim3(T_ / 64, 3, B_), 256, 0, stream>>>(z, Wq, bq, qws);
  attn_kernel<<<dim3(T_ / 64, 2, B_), 256, 0, stream>>>(qws, ktg, vtg, ows);
  proj_kernel<<<dim3(T_ / 64, 3, B_), 256, 0, stream>>>(ows, Wo, bo, out);
}

// Round 5
// 331.956 us; speedup vs baseline: 3.6744x; 1.1905x over previous
//
#include <hip/hip_runtime.h>

// R5: conflict-free packed-fragment LDS attention + register softmax + MFMA projections.
// f32 I/O (R2-verified). bf16 internals for Q/K/V/P and proj operands; f32 softmax/accum.
// All MFMA LDS tiles stored in fragment order: granule index == reading lane -> every
// ds_read_b128 is lane-contiguous (0 bank conflicts). Softmax lives on the D-layout in
// registers (quad-wide shfl_xor), P round-trips LDS within the same wave (no barrier).

typedef float  f32x4  __attribute__((ext_vector_type(4)));
typedef __bf16 bf16;
typedef __bf16 bf16x8 __attribute__((ext_vector_type(8)));

#define B_   16
#define D_   192
#define T_   4096
#define BANK 1000
#define SP   1024
#define DK   96
#define SCALE 0.10206207261596577f   // 1/sqrt(96)

// ---------------- K/V projection (tiny) ----------------
// ktg: [h][1024 s][96 i]   vtg: [h][96 i][1024 s]
__global__ __launch_bounds__(256) void kv_kernel(
    const float* __restrict__ mb, const float* __restrict__ Wk, const float* __restrict__ bk,
    const float* __restrict__ Wv, const float* __restrict__ bv,
    bf16* __restrict__ ktg, bf16* __restrict__ vtg) {
  int s = blockIdx.x * 256 + threadIdx.x;
  int o = blockIdx.y;
  int h = o / DK, i = o % DK;
  float ak = 0.f, av = 0.f;
  if (s < BANK) {
    ak = bk[o]; av = bv[o];
    for (int c = 0; c < D_; ++c) {
      float m = mb[c * BANK + s];
      ak += Wk[o * D_ + c] * m;
      av += Wv[o * D_ + c] * m;
    }
  }
  ktg[(size_t)(h * SP + s) * DK + i] = (bf16)ak;
  vtg[(size_t)(h * DK + i) * SP + s] = (bf16)av;
}

// ---------------- z transpose: z f32 [b][c][t] -> zT bf16 [b][t][c] ----------------
__global__ __launch_bounds__(256) void zt_kernel(const float* __restrict__ z,
                                                 bf16* __restrict__ zT) {
  __shared__ __align__(16) bf16 sT[64 * 200];
  const int tid = threadIdx.x;
  const int t0 = blockIdx.x * 64, b = blockIdx.y;
#pragma unroll
  for (int it = 0; it < 48; ++it) {          // 192c x 64t, coalesced along t
    int e = tid + 256 * it;
    int c = e >> 6, tl = e & 63;
    sT[tl * 200 + c] = (bf16)z[((size_t)b * D_ + c) * T_ + t0 + tl];
  }
  __syncthreads();
#pragma unroll
  for (int it = 0; it < 6; ++it) {           // 1536 granules of 8 bf16
    int g = tid + 256 * it;
    int tl = g / 24, c8 = (g % 24) * 8;
    bf16x8 v = *(const bf16x8*)&sT[tl * 200 + c8];
    *(bf16x8*)&zT[((size_t)b * T_ + t0 + tl) * D_ + c8] = v;
  }
}

// ---------------- MFMA projection: Y[b][o][t] = W · X + bias, times outscale ----------------
// XT bf16 [b][t][192 c]; W f32 [o][c]; Y f32 [b][o][t].
// Block: 64 o x 256 t; wave = 64 t (mt 0..3) x 64 o (nt 0..3). K chunks of 32.
__global__ __launch_bounds__(256) void proj_kernel(
    const bf16* __restrict__ XT, const float* __restrict__ W,
    const float* __restrict__ bias, float* __restrict__ Y, float outscale) {
  __shared__ __align__(16) char smem[40960];
  bf16* sA = (bf16*)smem;                    // per-chunk [16 tg][64 lane][8] = 16384 B
  bf16* sB = (bf16*)(smem + 16384);          // [6 kb][4 nt][64 lane][8]     = 24576 B
  float* sE = (float*)smem;                  // epilogue overlay: 4 waves x [16][68] f32

  const int tid = threadIdx.x;
  const int t0 = blockIdx.x * 256, o0 = blockIdx.y * 64, b = blockIdx.z;
  const int lane = tid & 63, wv = tid >> 6;
  const int quad = lane >> 4, l15 = lane & 15;

  // stage W (whole 64o x 192c) as packed B-frags, f32 -> bf16
#pragma unroll
  for (int r = 0; r < 6; ++r) {
    int g = tid + 256 * r;                   // [kb][nt][lane]
    int kb = g >> 8, nt = (g >> 6) & 3, qd = (g >> 4) & 3, l5 = g & 15;
    const float* wp = &W[(o0 + nt * 16 + l5) * D_ + kb * 32 + qd * 8];
    f32x4 wa = *(const f32x4*)wp, wb = *(const f32x4*)(wp + 4);
    bf16x8 pk;
#pragma unroll
    for (int u = 0; u < 4; ++u) { pk[u] = (bf16)wa[u]; pk[4 + u] = (bf16)wb[u]; }
    *(bf16x8*)&sB[(size_t)g * 8] = pk;
  }

  f32x4 acc[4][4];
#pragma unroll
  for (int m = 0; m < 4; ++m)
#pragma unroll
    for (int n = 0; n < 4; ++n) acc[m][n] = (f32x4){0.f, 0.f, 0.f, 0.f};

  for (int kb = 0; kb < 6; ++kb) {
    __syncthreads();                         // prev compute done (first: covers sB)
#pragma unroll
    for (int r = 0; r < 4; ++r) {            // stage A-chunk [tg 0..15][lane]
      int g = tid + 256 * r;
      int tg = g >> 6, qd = (g >> 4) & 3, l5 = g & 15;
      bf16x8 v = *(const bf16x8*)&XT[((size_t)b * T_ + t0 + tg * 16 + l5) * D_ +
                                     kb * 32 + qd * 8];
      *(bf16x8*)&sA[(size_t)g * 8] = v;
    }
    __syncthreads();
    bf16x8 bf[4];
#pragma unroll
    for (int n = 0; n < 4; ++n)
      bf[n] = *(const bf16x8*)&sB[(size_t)((kb * 4 + n) * 64 + lane) * 8];
#pragma unroll
    for (int m = 0; m < 4; ++m) {
      bf16x8 af = *(const bf16x8*)&sA[(size_t)((wv * 4 + m) * 64 + lane) * 8];
#pragma unroll
      for (int n = 0; n < 4; ++n)
        acc[m][n] = __builtin_amdgcn_mfma_f32_16x16x32_bf16(af, bf[n], acc[m][n], 0, 0, 0);
    }
  }
  __syncthreads();                           // before epilogue overlay

  // epilogue: per-wave LDS transpose, f32 coalesced stores
  float bs[4];
#pragma unroll
  for (int n = 0; n < 4; ++n) bs[n] = bias[o0 + n * 16 + l15];
  float* se = sE + wv * 1088;                // [16 t][68]
#pragma unroll
  for (int m = 0; m < 4; ++m) {
#pragma unroll
    for (int n = 0; n < 4; ++n)
#pragma unroll
      for (int r = 0; r < 4; ++r)
        se[(quad * 4 + r) * 68 + n * 16 + l15] = (acc[m][n][r] + bs[n]) * outscale;
    // same-wave DS in-order: no barrier needed
#pragma unroll
    for (int oo = 0; oo < 16; ++oo) {
      int ol = oo * 4 + quad;
      Y[((size_t)b * D_ + o0 + ol) * T_ + t0 + wv * 64 + m * 16 + l15] =
          se[l15 * 68 + ol];
    }
  }
}

// ---------------- packed-fragment bf16-MFMA flash attention ----------------
// Block = (b, h, 64 t); wave owns 16 t. Chunk = 64 s.
// All LDS tiles in fragment order: granule id == reading lane.
__global__ __launch_bounds__(256) void attn_kernel(
    const float* __restrict__ qws, const bf16* __restrict__ ktg,
    const bf16* __restrict__ vtg, bf16* __restrict__ owsT) {
  __shared__ __align__(16) char smem[45056];
  bf16* qt = (bf16*)smem;                    // [3 kb][4 w][64][8] = 12288
  bf16* kt = (bf16*)(smem + 12288);          // [3 kb][4 n][64][8] = 12288
  bf16* vt = (bf16*)(smem + 24576);          // [2 kb][6 n][64][8] = 12288
  bf16* sP = (bf16*)(smem + 36864);          // [2 kb][4 w][64][8] =  8192
  float* sO = (float*)smem;                  // epilogue overlay [96][68] f32 = 26112

  const int tid = threadIdx.x;
  const int t0 = blockIdx.x * 64, h = blockIdx.y, b = blockIdx.z;
  const int lane = tid & 63, wv = tid >> 6;
  const int quad = lane >> 4, l15 = lane & 15;

  // stage Q once (q already has SCALE folded by proj): f32 [o][t] -> packed A-frags
#pragma unroll
  for (int r = 0; r < 24; ++r) {
    int idx = tid + 256 * r;                 // 96 i x 64 t
    int i = idx >> 6, t = idx & 63;
    float v = qws[((size_t)(b * D_ + h * DK + i)) * T_ + t0 + t];
    int kb = i >> 5, qd = (i >> 3) & 3, j = i & 7, w = t >> 4, l5 = t & 15;
    qt[(size_t)(((kb * 4 + w) * 64 + qd * 16 + l5)) * 8 + j] = (bf16)v;
  }

  f32x4 oacc[6];
#pragma unroll
  for (int n = 0; n < 6; ++n) oacc[n] = (f32x4){0.f, 0.f, 0.f, 0.f};
  float m_run[4] = {-1e30f, -1e30f, -1e30f, -1e30f};
  float l_run[4] = {0.f, 0.f, 0.f, 0.f};

  const bf16* kb_g = ktg + (size_t)h * SP * DK;
  const bf16* vb_g = vtg + (size_t)h * DK * SP;

  for (int ch = 0; ch < 16; ++ch) {
    const int s0 = ch * 64;
    __syncthreads();                         // (A) prev readers done
#pragma unroll
    for (int r = 0; r < 3; ++r) {            // K chunk -> packed B-frags
      int g = tid + 256 * r;                 // [kb][n][lane]
      int kb = g >> 8, n = (g >> 6) & 3, qd = (g >> 4) & 3, l5 = g & 15;
      bf16x8 v = *(const bf16x8*)&kb_g[(size_t)(s0 + n * 16 + l5) * DK + kb * 32 + qd * 8];
      *(bf16x8*)&kt[(size_t)g * 8] = v;
    }
#pragma unroll
    for (int r = 0; r < 3; ++r) {            // V chunk -> packed B-frags
      int g = tid + 256 * r;                 // [kb][n(0..5)][lane]
      int gg = g >> 6;
      int kb = gg / 6, n = gg % 6, qd = (g >> 4) & 3, l5 = g & 15;
      bf16x8 v = *(const bf16x8*)&vb_g[(size_t)(n * 16 + l5) * SP + s0 + kb * 32 + qd * 8];
      *(bf16x8*)&vt[(size_t)g * 8] = v;
    }
    __syncthreads();                         // (B)

    // ---- QK^T (all frag reads lane-contiguous) ----
    f32x4 sacc[4];
#pragma unroll
    for (int n = 0; n < 4; ++n) sacc[n] = (f32x4){0.f, 0.f, 0.f, 0.f};
#pragma unroll
    for (int kb = 0; kb < 3; ++kb) {
      bf16x8 af = *(const bf16x8*)&qt[(size_t)((kb * 4 + wv) * 64 + lane) * 8];
#pragma unroll
      for (int n = 0; n < 4; ++n) {
        bf16x8 bfm = *(const bf16x8*)&kt[(size_t)((kb * 4 + n) * 64 + lane) * 8];
        sacc[n] = __builtin_amdgcn_mfma_f32_16x16x32_bf16(af, bfm, sacc[n], 0, 0, 0);
      }
    }
    if (ch == 15) {                          // mask s >= 1000 (s-local >= 40)
#pragma unroll
      for (int r = 0; r < 4; ++r) {
        if (l15 >= 8) sacc[2][r] = -1e30f;
        sacc[3][r] = -1e30f;
      }
    }

    // ---- register online softmax (row = 16 lanes of this quad) ----
    float pr[4][4];                          // [n][r]
#pragma unroll
    for (int r = 0; r < 4; ++r) {
      float mc = fmaxf(fmaxf(sacc[0][r], sacc[1][r]), fmaxf(sacc[2][r], sacc[3][r]));
      mc = fmaxf(mc, __shfl_xor(mc, 1, 64));
      mc = fmaxf(mc, __shfl_xor(mc, 2, 64));
      mc = fmaxf(mc, __shfl_xor(mc, 4, 64));
      mc = fmaxf(mc, __shfl_xor(mc, 8, 64));
      float mn = fmaxf(m_run[r], mc);
      float al = __expf(m_run[r] - mn);      // first chunk: exp(-1e30) = 0
      m_run[r] = mn;
      float ls = 0.f;
#pragma unroll
      for (int n = 0; n < 4; ++n) { pr[n][r] = __expf(sacc[n][r] - mn); ls += pr[n][r]; }
      ls += __shfl_xor(ls, 1, 64);
      ls += __shfl_xor(ls, 2, 64);
      ls += __shfl_xor(ls, 4, 64);
      ls += __shfl_xor(ls, 8, 64);
      l_run[r] = l_run[r] * al + ls;
#pragma unroll
      for (int n = 0; n < 6; ++n) oacc[n][r] *= al;
    }

    // ---- P -> packed A-frags in LDS (same-wave producer/consumer, no barrier) ----
#pragma unroll
    for (int n = 0; n < 4; ++n) {
      int kb = n >> 1, qd2 = ((n & 1) << 1) | (l15 >> 3), j = l15 & 7;
#pragma unroll
      for (int r = 0; r < 4; ++r)
        sP[(size_t)(((kb * 4 + wv) * 64 + qd2 * 16 + quad * 4 + r)) * 8 + j] =
            (bf16)pr[n][r];
    }

    // ---- PV ----
#pragma unroll
    for (int kb = 0; kb < 2; ++kb) {
      bf16x8 pa = *(const bf16x8*)&sP[(size_t)((kb * 4 + wv) * 64 + lane) * 8];
#pragma unroll
      for (int n = 0; n < 6; ++n) {
        bf16x8 vf = *(const bf16x8*)&vt[(size_t)((kb * 6 + n) * 64 + lane) * 8];
        oacc[n] = __builtin_amdgcn_mfma_f32_16x16x32_bf16(pa, vf, oacc[n], 0, 0, 0);
      }
    }
  }

  // ---- epilogue: /l, LDS transpose, bf16 [b][t][c] out ----
  float inv[4];
#pragma unroll
  for (int r = 0; r < 4; ++r) inv[r] = 1.0f / l_run[r];
  __syncthreads();
#pragma unroll
  for (int n = 0; n < 6; ++n)
#pragma unroll
    for (int r = 0; r < 4; ++r)
      sO[(n * 16 + l15) * 68 + wv * 16 + quad * 4 + r] = oacc[n][r] * inv[r];
  __syncthreads();
#pragma unroll
  for (int r = 0; r < 24; ++r) {
    int idx = tid + 256 * r;                 // 64 t x 96 i, i fast (coalesced out)
    int t = idx / 96, i = idx % 96;
    owsT[((size_t)b * T_ + t0 + t) * D_ + h * DK + i] = (bf16)sO[i * 68 + t];
  }
}

extern "C" void kernel_launch(void* const* d_in, const int* in_sizes, int n_in,
                              void* d_out, int out_size, void* d_ws, size_t ws_size,
                              hipStream_t stream) {
  const float* z  = (const float*)d_in[0];
  const float* mb = (const float*)d_in[1];
  const float* Wq = (const float*)d_in[2];
  const float* bq = (const float*)d_in[3];
  const float* Wk = (const float*)d_in[4];
  const float* bk = (const float*)d_in[5];
  const float* Wv = (const float*)d_in[6];
  const float* bv = (const float*)d_in[7];
  const float* Wo = (const float*)d_in[8];
  const float* bo = (const float*)d_in[9];
  float* out = (float*)d_out;

  // ws: ktg | vtg | zT | owsT (bf16)  then qws (f32)
  bf16* ktg  = (bf16*)d_ws;
  bf16* vtg  = ktg + 2 * SP * DK;
  bf16* zT   = vtg + 2 * DK * SP;
  bf16* owsT = zT + (size_t)B_ * T_ * D_;
  float* qws = (float*)(owsT + (size_t)B_ * T_ * D_);

  kv_kernel  <<<dim3(SP / 256, D_),    256, 0, stream>>>(mb, Wk, bk, Wv, bv, ktg, vtg);
  zt_kernel  <<<dim3(T_ / 64, B_),     256, 0, stream>>>(z, zT);
  proj_kernel<<<dim3(T_ / 256, 3, B_), 256, 0, stream>>>(zT, Wq, bq, qws, SCALE);
  attn_kernel<<<dim3(T_ / 64, 2, B_),  256, 0, stream>>>(qws, ktg, vtg, owsT);
  proj_kernel<<<dim3(T_ / 256, 3, B_), 256, 0, stream>>>(owsT, Wo, bo, out, 1.0f);
}